// Round 4
// baseline (41.888 us; speedup 1.0000x reference)
//
#include <hip/hip_runtime.h>
#include <limits.h>
#include <stdint.h>

#define SCAN_BS 1024
#define OBJ_PER 512              // objects per motion block
#define OBJ_BS  512              // threads per motion block
#define SLAB_F  (OBJ_PER * 21)   // 10752 floats = 43008 B
#define WIN     513              // offsets window entries (512 objects span <= 513 cavs)
#define SOFF_CH 9                // 9 chunks x 64 ints = 576 >= WIN

// ---- global->LDS DMA helpers (size must be literal) ----
__device__ __forceinline__ void gload_lds16(const void* g, void* l) {
    __builtin_amdgcn_global_load_lds(
        (const __attribute__((address_space(1))) uint32_t*)g,
        (__attribute__((address_space(3))) uint32_t*)l, 16, 0, 0);
}
__device__ __forceinline__ void gload_lds4(const void* g, void* l) {
    __builtin_amdgcn_global_load_lds(
        (const __attribute__((address_space(1))) uint32_t*)g,
        (__attribute__((address_space(3))) uint32_t*)l, 4, 0, 0);
}

// ---------------- fused scan: offsets + blockCav in ONE kernel ----------------
// Per-chunk block scan; publish chunk total via agent-scope atomic (flags[b] = total+1,
// 0 = not ready, flags pre-zeroed by memset node); one wave spins on predecessors.

__global__ __launch_bounds__(SCAN_BS) void scan_fused_kernel(
    const int* __restrict__ counts, int C,
    int* __restrict__ flags, int* __restrict__ offsets, int* __restrict__ blockCav) {

    __shared__ int sdata[SCAN_BS];
    __shared__ int carry_s;
    const int b = blockIdx.x;
    const int tid = threadIdx.x;
    const int gid = b * SCAN_BS + tid;
    const int v = (gid < C) ? counts[gid] : 0;

    sdata[tid] = v;
    __syncthreads();
    for (int ofs = 1; ofs < SCAN_BS; ofs <<= 1) {
        int add = (tid >= ofs) ? sdata[tid - ofs] : 0;
        __syncthreads();
        sdata[tid] += add;
        __syncthreads();
    }

    if (tid == SCAN_BS - 1)
        __hip_atomic_store(&flags[b], sdata[SCAN_BS - 1] + 1,
                           __ATOMIC_RELEASE, __HIP_MEMORY_SCOPE_AGENT);

    if (tid < 64) {
        int sum = 0;
        for (int p = tid; p < b; p += 64) {
            int f;
            do {
                f = __hip_atomic_load(&flags[p], __ATOMIC_ACQUIRE, __HIP_MEMORY_SCOPE_AGENT);
            } while (f == 0);
            sum += f - 1;
        }
        #pragma unroll
        for (int o = 32; o > 0; o >>= 1) sum += __shfl_down(sum, o, 64);
        if (tid == 0) carry_s = sum;
    }
    __syncthreads();

    if (gid < C) {
        const int end = sdata[tid] + carry_s;     // final inclusive cumsum
        offsets[gid] = end;
        const int start = end - v;
        int s0 = ((start + OBJ_PER - 1) / OBJ_PER) * OBJ_PER;
        for (int s = s0; s < end; s += OBJ_PER) blockCav[s / OBJ_PER] = gid;
    }
}

// ---------------- main per-object kernel ----------------
//
// out layout (floats):
//   [0,       8N)  obj_input  [1,N,2,4]
//   [8N,     10N)  query      [1,N,1,2]
//   [10N,    12N)  time_encode[N,2]
//   [12N,    13N)  target_time_diff [N]

__global__ __launch_bounds__(OBJ_BS) void motion_kernel(
    const float* __restrict__ bbx, const float* __restrict__ tint,
    const int* __restrict__ offsets, const int* __restrict__ blockCav,
    int C, int N, float* __restrict__ out) {

    __shared__ __align__(16) float sb[SLAB_F];      // 43008 B
    __shared__ int soff[SOFF_CH * 64];              // 576 ints

    const int tid  = threadIdx.x;
    const int lane = tid & 63;
    const int wid  = tid >> 6;
    const long long blockStart = (long long)blockIdx.x * OBJ_PER;
    const int nObjBlk = (int)min((long long)OBJ_PER, (long long)N - blockStart);

    const int c_lo = blockCav[blockIdx.x];          // only dependent pre-barrier load

    // ---- bbx slab DMA: fire-and-forget, issued before c_lo is needed ----
    const float* gsrc = bbx + blockStart * 21;
    const int nBytes = nObjBlk * 84;
    const int nCh = nBytes >> 10;                   // full 1KB wave-chunks (exact for 256/512)
    for (int ch = wid; ch < nCh; ch += 8)
        gload_lds16((const void*)(gsrc + ch * 256 + lane * 4), (void*)(sb + ch * 256));
    // scalar remainder (empty when nObjBlk is a multiple of 256)
    const int remF = (nBytes - (nCh << 10)) >> 2;
    for (int k = tid; k < remF; k += OBJ_BS) sb[nCh * 256 + k] = gsrc[nCh * 256 + k];

    // ---- offsets window DMA (clamped: always in-bounds & monotone, no sentinels) ----
    int c0 = min(c_lo, C - WIN); if (c0 < 0) c0 = 0;
    if (wid == 0) {
        #pragma unroll
        for (int ch = 0; ch < SOFF_CH; ++ch)
            gload_lds4((const void*)(offsets + c0 + ch * 64 + lane), (void*)(soff + ch * 64));
    }

    __syncthreads();   // single drain: all DMA + LDS visible

    if (tid >= nObjBlk) return;
    const int i = (int)(blockStart + tid);

    // binary search in LDS window: first j in [0,WIN) with soff[j] > i
    int lo = 0, hi = WIN;
    while (lo < hi) {
        int mid = (lo + hi) >> 1;
        if (soff[mid] > i) hi = mid; else lo = mid + 1;
    }
    const int cav = c0 + lo;

    // direct time gather (L2-local, high wave locality; off the staging critical path)
    const float t0 = tint[3 * cav + 0];
    const float t1 = tint[3 * cav + 1];
    const float t2 = tint[3 * cav + 2];

    // td_rep = [t2, t1, t0];  dt = time_encode
    const float dt0 = t1 - t2;
    const float dt1 = t0 - t1;

    // frames from LDS: frame k at sb[tid*21 + k*7 + {0,1}] (stride 21 -> conflict-free)
    const float* b = sb + tid * 21;
    const float x0 = b[0],  y0 = b[1];
    const float x1 = b[7],  y1 = b[8];
    const float x2 = b[14], y2 = b[15];

    // coords (flipped, normalized to last): c0v = f2-f0, c1v = f1-f0, c2v = 0
    const float c0x = x2 - x0, c0y = y2 - y0;
    const float c1x = x1 - x0, c1y = y1 - y0;

    const float d0x = c1x - c0x, d0y = c1y - c0y;
    const float d1x = 0.0f - c1x, d1y = 0.0f - c1y;

    const float s0x = d0x / dt0, s0y = d0y / dt0;
    const float s1x = d1x / dt1, s1y = d1y / dt1;

    const float last_len = 0.0f - (t1 - t0);
    const float safe_len = (last_len == 0.0f) ? 1.0f : last_len;
    const float exx = ((0.0f - c1x) * (0.0f - t0)) / safe_len;
    const float exy = ((0.0f - c1y) * (0.0f - t0)) / safe_len;
    const float qx = (last_len == 0.0f) ? 0.0f : exx;
    const float qy = (last_len == 0.0f) ? 0.0f : exy;

    // ---- writes (all coalesced) ----
    const size_t Ns = (size_t)N;
    float4* oi = (float4*)out;
    oi[(size_t)i * 2 + 0] = make_float4(d0x, d0y, s0x, s0y);
    oi[(size_t)i * 2 + 1] = make_float4(d1x, d1y, s1x, s1y);

    float2* q  = (float2*)(out + 8 * Ns);
    q[i] = make_float2(qx, qy);

    float2* te = (float2*)(out + 10 * Ns);
    te[i] = make_float2(dt0, dt1);

    out[12 * Ns + (size_t)i] = 0.0f - t0;
}

// ---------------- launch ----------------

extern "C" void kernel_launch(void* const* d_in, const int* in_sizes, int n_in,
                              void* d_out, int out_size, void* d_ws, size_t ws_size,
                              hipStream_t stream) {
    const float* bbx  = (const float*)d_in[0];   // [N,3,7]
    const float* tint = (const float*)d_in[1];   // [C*3]
    const int*   cnt  = (const int*)d_in[2];     // [C]
    float* out = (float*)d_out;

    const int N = in_sizes[0] / 21;
    const int C = in_sizes[2];

    const int nb  = (C + SCAN_BS - 1) / SCAN_BS;
    const int nob = (N + OBJ_PER - 1) / OBJ_PER;

    // ws layout: flags[pad 64] | offsets[C] | slack[128] (DMA overread lands here) | blockCav
    int* flags    = (int*)d_ws;
    int* offsets  = flags + ((nb + 63) & ~63);
    int* blockCav = offsets + C + 128;

    hipMemsetAsync(flags, 0, nb * sizeof(int), stream);
    scan_fused_kernel<<<nb, SCAN_BS, 0, stream>>>(cnt, C, flags, offsets, blockCav);
    motion_kernel<<<nob, OBJ_BS, 0, stream>>>(bbx, tint, offsets, blockCav, C, N, out);
}

// Round 5
// 38.892 us; speedup vs baseline: 1.0770x; 1.0770x over previous
//
#include <hip/hip_runtime.h>
#include <stdint.h>

#define SCAN_BS 1024
#define OBJ_BS  256
#define SLAB_F  (OBJ_BS * 21)     // 5376 floats = 21504 B
#define SLAB_CH (SLAB_F / 256)    // 21 wave-chunks (64 lanes x 16B)
#define WIN     257               // offsets window (256 objects span <= 257 cavs, counts>=1)
#define SOFF_CH 5                 // 5*64 = 320 ints staged (search touches only [0,257))

// ---- global->LDS DMA helpers (size must be a literal) ----
__device__ __forceinline__ void gload_lds16(const void* g, void* l) {
    __builtin_amdgcn_global_load_lds(
        (const __attribute__((address_space(1))) uint32_t*)g,
        (__attribute__((address_space(3))) uint32_t*)l, 16, 0, 0);
}
__device__ __forceinline__ void gload_lds4(const void* g, void* l) {
    __builtin_amdgcn_global_load_lds(
        (const __attribute__((address_space(1))) uint32_t*)g,
        (__attribute__((address_space(3))) uint32_t*)l, 4, 0, 0);
}

// ---------------- fused scan: ONE kernel, no inter-block deps ----------------
// Each block redundantly computes its carry = sum(counts[0 .. chunkStart)) with
// coalesced strided loads (L2-resident, 61x redundancy ~ 15 MB total = free),
// then block-scans its own chunk and emits offsets + blockCav.

__global__ __launch_bounds__(SCAN_BS) void scan_fused_kernel(
    const int* __restrict__ counts, int C,
    int* __restrict__ offsets, int* __restrict__ blockCav) {

    __shared__ int sdata[SCAN_BS];
    __shared__ int wsum[SCAN_BS / 64];

    const int tid  = threadIdx.x;
    const int lane = tid & 63;
    const int wid  = tid >> 6;
    const int b    = blockIdx.x;
    const int gid  = b * SCAN_BS + tid;
    const int chunkStart = b * SCAN_BS;

    const int v = (gid < C) ? counts[gid] : 0;
    sdata[tid] = v;

    // redundant carry: strided coalesced sum of all preceding counts
    int csum = 0;
    for (int idx = tid; idx < chunkStart; idx += SCAN_BS) csum += counts[idx];
    #pragma unroll
    for (int o = 32; o > 0; o >>= 1) csum += __shfl_down(csum, o, 64);
    if (lane == 0) wsum[wid] = csum;
    __syncthreads();

    // Hillis-Steele inclusive scan of the chunk
    for (int ofs = 1; ofs < SCAN_BS; ofs <<= 1) {
        int add = (tid >= ofs) ? sdata[tid - ofs] : 0;
        __syncthreads();
        sdata[tid] += add;
        __syncthreads();
    }

    // carry = sum of per-wave partials (wsum stable since first barrier; broadcast reads)
    int carry = 0;
    #pragma unroll
    for (int w = 0; w < SCAN_BS / 64; ++w) carry += wsum[w];

    if (gid < C) {
        const int end = sdata[tid] + carry;      // inclusive cumsum
        offsets[gid] = end;
        const int start = end - v;
        int s0 = ((start + OBJ_BS - 1) / OBJ_BS) * OBJ_BS;
        for (int s = s0; s < end; s += OBJ_BS) blockCav[s / OBJ_BS] = gid;
    }
}

// ---------------- main per-object kernel ----------------
//
// out layout (floats):
//   [0,       8N)  obj_input  [1,N,2,4]
//   [8N,     10N)  query      [1,N,1,2]
//   [10N,    12N)  time_encode[N,2]
//   [12N,    13N)  target_time_diff [N]

__global__ __launch_bounds__(OBJ_BS) void motion_kernel(
    const float* __restrict__ bbx, const float* __restrict__ tint,
    const int* __restrict__ offsets, const int* __restrict__ blockCav,
    int C, int N, float* __restrict__ out) {

    __shared__ __align__(16) float sb[SLAB_F];   // 21504 B
    __shared__ int soff[SOFF_CH * 64];           // 1280 B   -> 22.8 KB total, 7 blocks/CU

    const int tid  = threadIdx.x;
    const int lane = tid & 63;
    const int wid  = tid >> 6;
    const long long blockStart = (long long)blockIdx.x * OBJ_BS;
    const int nObjBlk = (int)min((long long)OBJ_BS, (long long)N - blockStart);

    // only dependent pre-barrier load (scalar); issued first
    const int c_lo = blockCav[blockIdx.x];

    // ---- bbx slab DMA: fire-and-forget, independent of c_lo ----
    const float* gsrc = bbx + blockStart * 21;
    if (nObjBlk == OBJ_BS) {
        #pragma unroll
        for (int ch = wid; ch < SLAB_CH; ch += 4)
            gload_lds16((const void*)(gsrc + ch * 256 + lane * 4), (void*)(sb + ch * 256));
    } else {
        // tail fallback (not hit when N % 256 == 0)
        const int nElem = nObjBlk * 21;
        for (int k = tid; k < nElem; k += OBJ_BS) sb[k] = gsrc[k];
    }

    // ---- offsets window DMA (clamped in-bounds & monotone; ws pads the 63-int overread) ----
    int c0 = min(c_lo, C - WIN); if (c0 < 0) c0 = 0;
    if (wid == 0) {
        #pragma unroll
        for (int ch = 0; ch < SOFF_CH; ++ch)
            gload_lds4((const void*)(offsets + c0 + ch * 64 + lane), (void*)(soff + ch * 64));
    }

    __syncthreads();   // single drain: all DMA visible

    if (tid >= nObjBlk) return;
    const int i = (int)(blockStart + tid);

    // binary search in LDS window: first j in [0,WIN) with soff[j] > i
    int lo = 0, hi = WIN;
    while (lo < hi) {
        int mid = (lo + hi) >> 1;
        if (soff[mid] > i) hi = mid; else lo = mid + 1;
    }
    const int cav = c0 + lo;

    // direct time gather (wave spans ~4 cavs -> L1/L2 broadcast; hidden by 28 waves/CU)
    const float t0 = tint[3 * cav + 0];
    const float t1 = tint[3 * cav + 1];
    const float t2 = tint[3 * cav + 2];

    // td_rep = [t2, t1, t0];  dt = time_encode
    const float dt0 = t1 - t2;
    const float dt1 = t0 - t1;

    // frames from LDS: frame k at sb[tid*21 + k*7 + {0,1}] (stride 21 -> conflict-free)
    const float* bp = sb + tid * 21;
    const float x0 = bp[0],  y0 = bp[1];
    const float x1 = bp[7],  y1 = bp[8];
    const float x2 = bp[14], y2 = bp[15];

    // coords (flipped, normalized to last): c0v = f2-f0, c1v = f1-f0, c2v = 0
    const float c0x = x2 - x0, c0y = y2 - y0;
    const float c1x = x1 - x0, c1y = y1 - y0;

    const float d0x = c1x - c0x, d0y = c1y - c0y;
    const float d1x = 0.0f - c1x, d1y = 0.0f - c1y;

    const float s0x = d0x / dt0, s0y = d0y / dt0;
    const float s1x = d1x / dt1, s1y = d1y / dt1;

    const float last_len = 0.0f - (t1 - t0);
    const float safe_len = (last_len == 0.0f) ? 1.0f : last_len;
    const float exx = ((0.0f - c1x) * (0.0f - t0)) / safe_len;
    const float exy = ((0.0f - c1y) * (0.0f - t0)) / safe_len;
    const float qx = (last_len == 0.0f) ? 0.0f : exx;
    const float qy = (last_len == 0.0f) ? 0.0f : exy;

    // ---- writes (all coalesced) ----
    const size_t Ns = (size_t)N;
    float4* oi = (float4*)out;
    oi[(size_t)i * 2 + 0] = make_float4(d0x, d0y, s0x, s0y);
    oi[(size_t)i * 2 + 1] = make_float4(d1x, d1y, s1x, s1y);

    float2* q  = (float2*)(out + 8 * Ns);
    q[i] = make_float2(qx, qy);

    float2* te = (float2*)(out + 10 * Ns);
    te[i] = make_float2(dt0, dt1);

    out[12 * Ns + (size_t)i] = 0.0f - t0;
}

// ---------------- launch ----------------

extern "C" void kernel_launch(void* const* d_in, const int* in_sizes, int n_in,
                              void* d_out, int out_size, void* d_ws, size_t ws_size,
                              hipStream_t stream) {
    const float* bbx  = (const float*)d_in[0];   // [N,3,7]
    const float* tint = (const float*)d_in[1];   // [C*3]
    const int*   cnt  = (const int*)d_in[2];     // [C]
    float* out = (float*)d_out;

    const int N = in_sizes[0] / 21;
    const int C = in_sizes[2];

    const int nb  = (C + SCAN_BS - 1) / SCAN_BS;
    const int nob = (N + OBJ_BS - 1) / OBJ_BS;

    // ws layout: offsets[C] | pad 64 ints (absorbs window-DMA overread) | blockCav[nob]
    int* offsets  = (int*)d_ws;
    int* blockCav = offsets + C + 64;

    scan_fused_kernel<<<nb, SCAN_BS, 0, stream>>>(cnt, C, offsets, blockCav);
    motion_kernel<<<nob, OBJ_BS, 0, stream>>>(bbx, tint, offsets, blockCav, C, N, out);
}